// Round 1
// baseline (1878.068 us; speedup 1.0000x reference)
//
#include <hip/hip_runtime.h>

// ---------------------------------------------------------------------------
// GCN 2-layer: h1 = norm_adj(xW1)+b1 -> relu -> h2 = norm_adj(h1W2)+b2 -> logsoftmax
// norm_adj uses D^{-1/2}(A+I)D^{-1/2} with weighted in-degree (incl. self loop).
// Scatter phase uses native fp32 global atomics (unsafeAtomicAdd).
// ---------------------------------------------------------------------------

__global__ void k_fill1(float* __restrict__ p, int n) {
    int i = blockIdx.x * blockDim.x + threadIdx.x;
    if (i < n) p[i] = 1.0f;
}

__global__ void k_deg_accum(const int* __restrict__ dst, const float* __restrict__ ew,
                            float* __restrict__ deg, int E) {
    int e = blockIdx.x * blockDim.x + threadIdx.x;
    if (e < E) unsafeAtomicAdd(&deg[dst[e]], ew[e]);
}

__global__ void k_rsqrt_(float* __restrict__ p, int n) {
    int i = blockIdx.x * blockDim.x + threadIdx.x;
    if (i < n) p[i] = rsqrtf(p[i]);  // deg >= 1 always (self loop)
}

// h[n][64] = x[n][128] @ W[128][64]; W fully LDS-resident, 16 nodes/block
__global__ __launch_bounds__(256) void k_gemm1(const float* __restrict__ x,
                                               const float* __restrict__ W,
                                               float* __restrict__ h, int n) {
    __shared__ float Ws[128 * 64];
    __shared__ float xs[16][128];
    const int t = threadIdx.x;
    for (int i = t; i < 128 * 64; i += 256) Ws[i] = W[i];
    const int node0 = blockIdx.x * 16;
    for (int i = t; i < 16 * 128; i += 256) {
        int nn = i >> 7, kk = i & 127;
        int node = node0 + nn;
        xs[nn][kk] = (node < n) ? x[(size_t)node * 128 + kk] : 0.0f;
    }
    __syncthreads();
    const int f = t & 63;
    const int ng = t >> 6;  // 0..3; whole wave shares ng -> xs reads broadcast
    float a0 = 0.f, a1 = 0.f, a2 = 0.f, a3 = 0.f;
#pragma unroll 4
    for (int k = 0; k < 128; ++k) {
        float wv = Ws[k * 64 + f];
        a0 = fmaf(xs[ng][k], wv, a0);
        a1 = fmaf(xs[ng + 4][k], wv, a1);
        a2 = fmaf(xs[ng + 8][k], wv, a2);
        a3 = fmaf(xs[ng + 12][k], wv, a3);
    }
    if (node0 + ng < n)      h[(size_t)(node0 + ng) * 64 + f] = a0;
    if (node0 + ng + 4 < n)  h[(size_t)(node0 + ng + 4) * 64 + f] = a1;
    if (node0 + ng + 8 < n)  h[(size_t)(node0 + ng + 8) * 64 + f] = a2;
    if (node0 + ng + 12 < n) h[(size_t)(node0 + ng + 12) * 64 + f] = a3;
}

// agg[i] = h[i] * dinv[node]^2  (self-loop term), float4-granular
__global__ void k_init_agg(const float4* __restrict__ h, const float* __restrict__ dinv,
                           float4* __restrict__ agg, int total4, int shift2) {
    int i = blockIdx.x * blockDim.x + threadIdx.x;
    if (i >= total4) return;
    float di = dinv[i >> shift2];
    float s = di * di;
    float4 v = h[i];
    v.x *= s; v.y *= s; v.z *= s; v.w *= s;
    agg[i] = v;
}

// One work-item per (edge, float4-chunk). FV = F/4 chunks per row.
template <int FV>
__global__ __launch_bounds__(256) void k_scatter(const int* __restrict__ src,
                                                 const int* __restrict__ dst,
                                                 const float* __restrict__ ew,
                                                 const float* __restrict__ dinv,
                                                 const float* __restrict__ h,
                                                 float* __restrict__ agg, int E) {
    int w = blockIdx.x * blockDim.x + threadIdx.x;
    if (w >= E * FV) return;  // E*FV <= 25.6M, fits int32
    int e = w >> (FV == 16 ? 4 : 2);
    int c = w & (FV - 1);
    int s = src[e], d = dst[e];
    float norm = dinv[s] * ew[e] * dinv[d];
    float4 hv = ((const float4*)h)[s * FV + c];
    float* ap = agg + ((size_t)d * FV + c) * 4;
    unsafeAtomicAdd(ap + 0, hv.x * norm);
    unsafeAtomicAdd(ap + 1, hv.y * norm);
    unsafeAtomicAdd(ap + 2, hv.z * norm);
    unsafeAtomicAdd(ap + 3, hv.w * norm);
}

// h2[n][16] = relu(a[n][64] + b1) @ W[64][16]; bias+relu fused into LDS load.
// xs padded 64->68 so the 4 distinct ng-group addresses per wave hit 4 banks.
__global__ __launch_bounds__(256) void k_gemm2(const float* __restrict__ a,
                                               const float* __restrict__ W,
                                               const float* __restrict__ b1,
                                               float* __restrict__ h2, int n) {
    __shared__ float Ws[64 * 16];
    __shared__ float xs[32][68];
    const int t = threadIdx.x;
    for (int i = t; i < 64 * 16; i += 256) Ws[i] = W[i];
    const int node0 = blockIdx.x * 32;
    for (int i = t; i < 32 * 64; i += 256) {
        int nn = i >> 6, kk = i & 63;
        int node = node0 + nn;
        xs[nn][kk] = (node < n) ? fmaxf(a[(size_t)node * 64 + kk] + b1[kk], 0.0f) : 0.0f;
    }
    __syncthreads();
    const int f = t & 15;
    const int ng = t >> 4;  // 0..15
    float a0 = 0.f, a1 = 0.f;
#pragma unroll 4
    for (int k = 0; k < 64; ++k) {
        float wv = Ws[k * 16 + f];
        a0 = fmaf(xs[ng][k], wv, a0);
        a1 = fmaf(xs[ng + 16][k], wv, a1);
    }
    if (node0 + ng < n)      h2[(size_t)(node0 + ng) * 16 + f] = a0;
    if (node0 + ng + 16 < n) h2[(size_t)(node0 + ng + 16) * 16 + f] = a1;
}

// In-place: out[i][:] = log_softmax(out[i][:] + b2)
__global__ void k_logsoftmax(float* __restrict__ out, const float* __restrict__ b2, int n) {
    int i = blockIdx.x * blockDim.x + threadIdx.x;
    if (i >= n) return;
    const size_t base = (size_t)i * 16;
    float v[16];
#pragma unroll
    for (int f = 0; f < 16; ++f) v[f] = out[base + f] + b2[f];
    float m = v[0];
#pragma unroll
    for (int f = 1; f < 16; ++f) m = fmaxf(m, v[f]);
    float s = 0.f;
#pragma unroll
    for (int f = 0; f < 16; ++f) s += __expf(v[f] - m);
    float lse = __logf(s);
#pragma unroll
    for (int f = 0; f < 16; ++f) out[base + f] = v[f] - m - lse;
}

extern "C" void kernel_launch(void* const* d_in, const int* in_sizes, int n_in,
                              void* d_out, int out_size, void* d_ws, size_t ws_size,
                              hipStream_t stream) {
    const float* x  = (const float*)d_in[0];
    const int*   ei = (const int*)d_in[1];   // [2, E] int
    const float* ew = (const float*)d_in[2];
    const float* W1 = (const float*)d_in[3];
    const float* b1 = (const float*)d_in[4];
    const float* W2 = (const float*)d_in[5];
    const float* b2 = (const float*)d_in[6];
    float* out = (float*)d_out;

    const int n = in_sizes[0] / 128;  // 100000
    const int E = in_sizes[2];        // 1600000
    const int* srcv = ei;
    const int* dstv = ei + E;

    // Workspace layout (floats): dinv[n] | h1[n*64] (reused as h2[n*16]) | agg1[n*64]
    float* dinv = (float*)d_ws;
    float* h1   = dinv + n;
    float* agg1 = h1 + (size_t)n * 64;

    // Degree + normalization
    k_fill1<<<(n + 255) / 256, 256, 0, stream>>>(dinv, n);
    k_deg_accum<<<(E + 255) / 256, 256, 0, stream>>>(dstv, ew, dinv, E);
    k_rsqrt_<<<(n + 255) / 256, 256, 0, stream>>>(dinv, n);

    // Layer 1
    k_gemm1<<<(n + 15) / 16, 256, 0, stream>>>(x, W1, h1, n);
    k_init_agg<<<(n * 16 + 255) / 256, 256, 0, stream>>>((const float4*)h1, dinv,
                                                         (float4*)agg1, n * 16, 4);
    {
        long long work = (long long)E * 16;
        k_scatter<16><<<(int)((work + 255) / 256), 256, 0, stream>>>(srcv, dstv, ew, dinv,
                                                                     h1, agg1, E);
    }

    // Layer 2 (h2 reuses h1's buffer; gemm2 fuses bias1+relu on load)
    k_gemm2<<<(n + 31) / 32, 256, 0, stream>>>(agg1, W2, b1, h1, n);
    k_init_agg<<<(n * 4 + 255) / 256, 256, 0, stream>>>((const float4*)h1, dinv,
                                                        (float4*)out, n * 4, 2);
    {
        long long work = (long long)E * 4;
        k_scatter<4><<<(int)((work + 255) / 256), 256, 0, stream>>>(srcv, dstv, ew, dinv,
                                                                    h1, out, E);
    }

    // Epilogue: + b2, log_softmax, in place on d_out
    k_logsoftmax<<<(n + 255) / 256, 256, 0, stream>>>(out, b2, n);
}

// Round 2
// 736.155 us; speedup vs baseline: 2.5512x; 2.5512x over previous
//
#include <hip/hip_runtime.h>

// ---------------------------------------------------------------------------
// GCN 2-layer, CSR-gather formulation (no fp32 scatter atomics).
// Per call: deg/dinv -> CSR build (hist + scan + cursor scatter) ->
//   gemm1 -> gather-agg (F=64) -> gemm2(+bias+relu) -> gather-agg (F=16,
//   into d_out) -> +b2 + log_softmax in place.
// ---------------------------------------------------------------------------

__global__ void k_fill1(float* __restrict__ p, int n) {
    int i = blockIdx.x * blockDim.x + threadIdx.x;
    if (i < n) p[i] = 1.0f;
}

__global__ void k_zero(int* __restrict__ p, int n) {
    int i = blockIdx.x * blockDim.x + threadIdx.x;
    if (i < n) p[i] = 0;
}

__global__ void k_deg_accum(const int* __restrict__ dst, const float* __restrict__ ew,
                            float* __restrict__ deg, int E) {
    int e = blockIdx.x * blockDim.x + threadIdx.x;
    if (e < E) unsafeAtomicAdd(&deg[dst[e]], ew[e]);
}

__global__ void k_rsqrt_(float* __restrict__ p, int n) {
    int i = blockIdx.x * blockDim.x + threadIdx.x;
    if (i < n) p[i] = rsqrtf(p[i]);  // deg >= 1 always (self loop)
}

__global__ void k_hist(const int* __restrict__ dst, int* __restrict__ cnt, int E) {
    int e = blockIdx.x * blockDim.x + threadIdx.x;
    if (e < E) atomicAdd(&cnt[dst[e]], 1);
}

// Single-block exclusive scan: cnt[n] -> rowptr[n+1]. 1024 threads, chunked.
__global__ __launch_bounds__(1024) void k_scan(const int* __restrict__ cnt,
                                               int* __restrict__ rowptr, int n) {
    __shared__ int sums[1024];
    const int t = threadIdx.x;
    const int chunk = (n + 1023) / 1024;
    const int lo = t * chunk;
    const int hi = min(lo + chunk, n);
    int s = 0;
    for (int i = lo; i < hi; ++i) s += cnt[i];
    sums[t] = s;
    __syncthreads();
    for (int off = 1; off < 1024; off <<= 1) {
        int u = (t >= off) ? sums[t - off] : 0;
        __syncthreads();
        sums[t] += u;
        __syncthreads();
    }
    int excl = (t == 0) ? 0 : sums[t - 1];
    for (int i = lo; i < hi; ++i) {
        rowptr[i] = excl;
        excl += cnt[i];
    }
    if (t == 1023) rowptr[n] = sums[1023];
}

__global__ void k_copy_i(const int* __restrict__ a, int* __restrict__ b, int n) {
    int i = blockIdx.x * blockDim.x + threadIdx.x;
    if (i < n) b[i] = a[i];
}

// Bucket edges by dst: es[p]=src, enorm[p]=dinv[src]*w*dinv[dst]
__global__ void k_build(const int* __restrict__ src, const int* __restrict__ dst,
                        const float* __restrict__ ew, const float* __restrict__ dinv,
                        int* __restrict__ cursor, int* __restrict__ es,
                        float* __restrict__ enorm, int E) {
    int e = blockIdx.x * blockDim.x + threadIdx.x;
    if (e >= E) return;
    int s = src[e], d = dst[e];
    int p = atomicAdd(&cursor[d], 1);
    es[p] = s;
    enorm[p] = dinv[s] * ew[e] * dinv[d];
}

// h[n][64] = x[n][128] @ W[128][64]; W fully LDS-resident, 16 nodes/block
__global__ __launch_bounds__(256) void k_gemm1(const float* __restrict__ x,
                                               const float* __restrict__ W,
                                               float* __restrict__ h, int n) {
    __shared__ float Ws[128 * 64];
    __shared__ float xs[16][128];
    const int t = threadIdx.x;
    for (int i = t; i < 128 * 64; i += 256) Ws[i] = W[i];
    const int node0 = blockIdx.x * 16;
    for (int i = t; i < 16 * 128; i += 256) {
        int nn = i >> 7, kk = i & 127;
        int node = node0 + nn;
        xs[nn][kk] = (node < n) ? x[(size_t)node * 128 + kk] : 0.0f;
    }
    __syncthreads();
    const int f = t & 63;
    const int ng = t >> 6;  // 0..3; whole wave shares ng -> xs reads broadcast
    float a0 = 0.f, a1 = 0.f, a2 = 0.f, a3 = 0.f;
#pragma unroll 4
    for (int k = 0; k < 128; ++k) {
        float wv = Ws[k * 64 + f];
        a0 = fmaf(xs[ng][k], wv, a0);
        a1 = fmaf(xs[ng + 4][k], wv, a1);
        a2 = fmaf(xs[ng + 8][k], wv, a2);
        a3 = fmaf(xs[ng + 12][k], wv, a3);
    }
    if (node0 + ng < n)      h[(size_t)(node0 + ng) * 64 + f] = a0;
    if (node0 + ng + 4 < n)  h[(size_t)(node0 + ng + 4) * 64 + f] = a1;
    if (node0 + ng + 8 < n)  h[(size_t)(node0 + ng + 8) * 64 + f] = a2;
    if (node0 + ng + 12 < n) h[(size_t)(node0 + ng + 12) * 64 + f] = a3;
}

// Gather-aggregate, F=64: one wave per node, lane = feature.
__global__ __launch_bounds__(256) void k_agg64(const float* __restrict__ h,
                                               const int* __restrict__ rowptr,
                                               const int* __restrict__ es,
                                               const float* __restrict__ enorm,
                                               const float* __restrict__ dinv,
                                               float* __restrict__ agg, int n) {
    const int node = (blockIdx.x * 256 + threadIdx.x) >> 6;
    const int lane = threadIdx.x & 63;
    if (node >= n) return;
    const float di = dinv[node];
    float acc = h[(size_t)node * 64 + lane] * di * di;  // self loop
    const int lo = rowptr[node], hi = rowptr[node + 1];
    int i = lo;
    for (; i + 1 < hi; i += 2) {
        int s0 = es[i], s1 = es[i + 1];
        float w0 = enorm[i], w1 = enorm[i + 1];
        float v0 = h[(size_t)s0 * 64 + lane];
        float v1 = h[(size_t)s1 * 64 + lane];
        acc = fmaf(v0, w0, acc);
        acc = fmaf(v1, w1, acc);
    }
    if (i < hi) {
        acc = fmaf(h[(size_t)es[i] * 64 + lane], enorm[i], acc);
    }
    agg[(size_t)node * 64 + lane] = acc;
}

// Gather-aggregate, F=16: one 16-lane group per node.
__global__ __launch_bounds__(256) void k_agg16(const float* __restrict__ h,
                                               const int* __restrict__ rowptr,
                                               const int* __restrict__ es,
                                               const float* __restrict__ enorm,
                                               const float* __restrict__ dinv,
                                               float* __restrict__ agg, int n) {
    const int node = (blockIdx.x * 256 + threadIdx.x) >> 4;
    const int lane = threadIdx.x & 15;
    if (node >= n) return;
    const float di = dinv[node];
    float acc = h[(size_t)node * 16 + lane] * di * di;  // self loop
    const int lo = rowptr[node], hi = rowptr[node + 1];
    int i = lo;
    for (; i + 1 < hi; i += 2) {
        int s0 = es[i], s1 = es[i + 1];
        float w0 = enorm[i], w1 = enorm[i + 1];
        float v0 = h[(size_t)s0 * 16 + lane];
        float v1 = h[(size_t)s1 * 16 + lane];
        acc = fmaf(v0, w0, acc);
        acc = fmaf(v1, w1, acc);
    }
    if (i < hi) {
        acc = fmaf(h[(size_t)es[i] * 16 + lane], enorm[i], acc);
    }
    agg[(size_t)node * 16 + lane] = acc;
}

// h2[n][16] = relu(a[n][64] + b1) @ W[64][16]; bias+relu fused into LDS load.
__global__ __launch_bounds__(256) void k_gemm2(const float* __restrict__ a,
                                               const float* __restrict__ W,
                                               const float* __restrict__ b1,
                                               float* __restrict__ h2, int n) {
    __shared__ float Ws[64 * 16];
    __shared__ float xs[32][68];
    const int t = threadIdx.x;
    for (int i = t; i < 64 * 16; i += 256) Ws[i] = W[i];
    const int node0 = blockIdx.x * 32;
    for (int i = t; i < 32 * 64; i += 256) {
        int nn = i >> 6, kk = i & 63;
        int node = node0 + nn;
        xs[nn][kk] = (node < n) ? fmaxf(a[(size_t)node * 64 + kk] + b1[kk], 0.0f) : 0.0f;
    }
    __syncthreads();
    const int f = t & 15;
    const int ng = t >> 4;  // 0..15
    float a0 = 0.f, a1 = 0.f;
#pragma unroll 4
    for (int k = 0; k < 64; ++k) {
        float wv = Ws[k * 16 + f];
        a0 = fmaf(xs[ng][k], wv, a0);
        a1 = fmaf(xs[ng + 16][k], wv, a1);
    }
    if (node0 + ng < n)      h2[(size_t)(node0 + ng) * 16 + f] = a0;
    if (node0 + ng + 16 < n) h2[(size_t)(node0 + ng + 16) * 16 + f] = a1;
}

// In-place: out[i][:] = log_softmax(out[i][:] + b2)
__global__ void k_logsoftmax(float* __restrict__ out, const float* __restrict__ b2, int n) {
    int i = blockIdx.x * blockDim.x + threadIdx.x;
    if (i >= n) return;
    const size_t base = (size_t)i * 16;
    float v[16];
#pragma unroll
    for (int f = 0; f < 16; ++f) v[f] = out[base + f] + b2[f];
    float m = v[0];
#pragma unroll
    for (int f = 1; f < 16; ++f) m = fmaxf(m, v[f]);
    float s = 0.f;
#pragma unroll
    for (int f = 0; f < 16; ++f) s += __expf(v[f] - m);
    float lse = __logf(s);
#pragma unroll
    for (int f = 0; f < 16; ++f) out[base + f] = v[f] - m - lse;
}

extern "C" void kernel_launch(void* const* d_in, const int* in_sizes, int n_in,
                              void* d_out, int out_size, void* d_ws, size_t ws_size,
                              hipStream_t stream) {
    const float* x  = (const float*)d_in[0];
    const int*   ei = (const int*)d_in[1];   // [2, E]
    const float* ew = (const float*)d_in[2];
    const float* W1 = (const float*)d_in[3];
    const float* b1 = (const float*)d_in[4];
    const float* W2 = (const float*)d_in[5];
    const float* b2 = (const float*)d_in[6];
    float* out = (float*)d_out;

    const int n = in_sizes[0] / 128;  // 100000
    const int E = in_sizes[2];        // 1600000
    const int* srcv = ei;
    const int* dstv = ei + E;

    // Workspace layout (4B elems):
    // dinv[n] | h1[n*64] | agg1[n*64] | rowptr[n+1] | cnt[n] | cursor[n] | es[E] | enorm[E]
    float* dinv   = (float*)d_ws;
    float* h1     = dinv + n;            // reused as h2[n*16] in layer 2
    float* agg1   = h1 + (size_t)n * 64;
    int*   rowptr = (int*)(agg1 + (size_t)n * 64);
    int*   cnt    = rowptr + (n + 1);
    int*   cursor = cnt + n;
    int*   es     = cursor + n;
    float* enorm  = (float*)(es + E);

    const int TB = 256;
    // --- degree + dinv ---
    k_fill1<<<(n + TB - 1) / TB, TB, 0, stream>>>(dinv, n);
    k_deg_accum<<<(E + TB - 1) / TB, TB, 0, stream>>>(dstv, ew, dinv, E);
    k_rsqrt_<<<(n + TB - 1) / TB, TB, 0, stream>>>(dinv, n);

    // --- CSR build (bucket by dst) ---
    k_zero<<<(n + TB - 1) / TB, TB, 0, stream>>>(cnt, n);
    k_hist<<<(E + TB - 1) / TB, TB, 0, stream>>>(dstv, cnt, E);
    k_scan<<<1, 1024, 0, stream>>>(cnt, rowptr, n);
    k_copy_i<<<(n + TB - 1) / TB, TB, 0, stream>>>(rowptr, cursor, n);
    k_build<<<(E + TB - 1) / TB, TB, 0, stream>>>(srcv, dstv, ew, dinv, cursor, es, enorm, E);

    // --- layer 1: gemm + gather-agg ---
    k_gemm1<<<(n + 15) / 16, TB, 0, stream>>>(x, W1, h1, n);
    k_agg64<<<(n * 64 + TB - 1) / TB, TB, 0, stream>>>(h1, rowptr, es, enorm, dinv, agg1, n);

    // --- layer 2: gemm(+bias1+relu) + gather-agg into d_out ---
    k_gemm2<<<(n + 31) / 32, TB, 0, stream>>>(agg1, W2, b1, h1, n);
    k_agg16<<<(n * 16 + TB - 1) / TB, TB, 0, stream>>>(h1, rowptr, es, enorm, dinv, out, n);

    // --- epilogue ---
    k_logsoftmax<<<(n + TB - 1) / TB, TB, 0, stream>>>(out, b2, n);
}

// Round 3
// 517.436 us; speedup vs baseline: 3.6296x; 1.4227x over previous
//
#include <hip/hip_runtime.h>

// ---------------------------------------------------------------------------
// GCN 2-layer, CSR-gather formulation.
// R3: multi-block scan (was 167us single-block), fused deg+hist pass,
//     int2-packed edge records, x4-unrolled gather loops.
// ---------------------------------------------------------------------------

__global__ void k_init(float* __restrict__ dinv, int* __restrict__ cnt, int n) {
    int i = blockIdx.x * blockDim.x + threadIdx.x;
    if (i < n) { dinv[i] = 1.0f; cnt[i] = 0; }
}

// One pass over dst: weighted degree (float atomic) + histogram (int atomic)
__global__ void k_deg_hist(const int* __restrict__ dst, const float* __restrict__ ew,
                           float* __restrict__ deg, int* __restrict__ cnt, int E) {
    int e = blockIdx.x * blockDim.x + threadIdx.x;
    if (e >= E) return;
    int d = dst[e];
    unsafeAtomicAdd(&deg[d], ew[e]);
    atomicAdd(&cnt[d], 1);
}

__global__ void k_rsqrt_(float* __restrict__ p, int n) {
    int i = blockIdx.x * blockDim.x + threadIdx.x;
    if (i < n) p[i] = rsqrtf(p[i]);  // deg >= 1 always (self loop)
}

// ---- 3-phase scan: cnt[n] -> rowptr[n+1] (+ cursor copy) ----
#define SCAN_BS 256
#define SCAN_ITEMS 4
#define SCAN_CHUNK (SCAN_BS * SCAN_ITEMS)  // 1024

__global__ __launch_bounds__(SCAN_BS) void k_scanA(const int* __restrict__ cnt,
                                                   int* __restrict__ bsum, int n) {
    __shared__ int red[SCAN_BS];
    const int b = blockIdx.x, t = threadIdx.x;
    const int base = b * SCAN_CHUNK + t * SCAN_ITEMS;
    int s = 0;
#pragma unroll
    for (int j = 0; j < SCAN_ITEMS; ++j) {
        int i = base + j;
        if (i < n) s += cnt[i];
    }
    red[t] = s;
    __syncthreads();
    for (int off = SCAN_BS / 2; off > 0; off >>= 1) {
        if (t < off) red[t] += red[t + off];
        __syncthreads();
    }
    if (t == 0) bsum[b] = red[0];
}

// Single small block: exclusive scan of bsum[nb] -> boff[nb]; rowptr[n] = total.
__global__ __launch_bounds__(128) void k_scanB(const int* __restrict__ bsum,
                                               int* __restrict__ boff,
                                               int* __restrict__ rowptr, int nb, int n) {
    __shared__ int lds[128];
    const int t = threadIdx.x;
    int carry = 0;
    for (int base = 0; base < nb; base += 128) {
        int idx = base + t;
        int v = (idx < nb) ? bsum[idx] : 0;
        lds[t] = v;
        __syncthreads();
        for (int off = 1; off < 128; off <<= 1) {
            int u = (t >= off) ? lds[t - off] : 0;
            __syncthreads();
            lds[t] += u;
            __syncthreads();
        }
        if (idx < nb) boff[idx] = lds[t] - v + carry;
        carry += lds[127];
        __syncthreads();
    }
    if (t == 0) rowptr[n] = carry;
}

__global__ __launch_bounds__(SCAN_BS) void k_scanC(const int* __restrict__ cnt,
                                                   const int* __restrict__ boff,
                                                   int* __restrict__ rowptr,
                                                   int* __restrict__ cursor, int n) {
    __shared__ int lds[SCAN_BS];
    const int b = blockIdx.x, t = threadIdx.x;
    const int base = b * SCAN_CHUNK + t * SCAN_ITEMS;
    int v[SCAN_ITEMS];
    int s = 0;
#pragma unroll
    for (int j = 0; j < SCAN_ITEMS; ++j) {
        int i = base + j;
        v[j] = (i < n) ? cnt[i] : 0;
        s += v[j];
    }
    lds[t] = s;
    __syncthreads();
    for (int off = 1; off < SCAN_BS; off <<= 1) {
        int u = (t >= off) ? lds[t - off] : 0;
        __syncthreads();
        lds[t] += u;
        __syncthreads();
    }
    int excl = lds[t] - s + boff[b];
#pragma unroll
    for (int j = 0; j < SCAN_ITEMS; ++j) {
        int i = base + j;
        if (i < n) {
            rowptr[i] = excl;
            cursor[i] = excl;
            excl += v[j];
        }
    }
}

// Bucket edges by dst: epack[p] = {src, bitcast(norm)} — single 8B store.
__global__ void k_build(const int* __restrict__ src, const int* __restrict__ dst,
                        const float* __restrict__ ew, const float* __restrict__ dinv,
                        int* __restrict__ cursor, int2* __restrict__ epack, int E) {
    int e = blockIdx.x * blockDim.x + threadIdx.x;
    if (e >= E) return;
    int s = src[e], d = dst[e];
    int p = atomicAdd(&cursor[d], 1);
    int2 pk;
    pk.x = s;
    pk.y = __float_as_int(dinv[s] * ew[e] * dinv[d]);
    epack[p] = pk;
}

// h[n][64] = x[n][128] @ W[128][64]; W fully LDS-resident, 16 nodes/block
__global__ __launch_bounds__(256) void k_gemm1(const float* __restrict__ x,
                                               const float* __restrict__ W,
                                               float* __restrict__ h, int n) {
    __shared__ float Ws[128 * 64];
    __shared__ float xs[16][128];
    const int t = threadIdx.x;
    for (int i = t; i < 128 * 64; i += 256) Ws[i] = W[i];
    const int node0 = blockIdx.x * 16;
    for (int i = t; i < 16 * 128; i += 256) {
        int nn = i >> 7, kk = i & 127;
        int node = node0 + nn;
        xs[nn][kk] = (node < n) ? x[(size_t)node * 128 + kk] : 0.0f;
    }
    __syncthreads();
    const int f = t & 63;
    const int ng = t >> 6;  // 0..3; whole wave shares ng -> xs reads broadcast
    float a0 = 0.f, a1 = 0.f, a2 = 0.f, a3 = 0.f;
#pragma unroll 4
    for (int k = 0; k < 128; ++k) {
        float wv = Ws[k * 64 + f];
        a0 = fmaf(xs[ng][k], wv, a0);
        a1 = fmaf(xs[ng + 4][k], wv, a1);
        a2 = fmaf(xs[ng + 8][k], wv, a2);
        a3 = fmaf(xs[ng + 12][k], wv, a3);
    }
    if (node0 + ng < n)      h[(size_t)(node0 + ng) * 64 + f] = a0;
    if (node0 + ng + 4 < n)  h[(size_t)(node0 + ng + 4) * 64 + f] = a1;
    if (node0 + ng + 8 < n)  h[(size_t)(node0 + ng + 8) * 64 + f] = a2;
    if (node0 + ng + 12 < n) h[(size_t)(node0 + ng + 12) * 64 + f] = a3;
}

// Gather-aggregate, F=64: one wave per node, lane = feature. x4 unroll for MLP.
__global__ __launch_bounds__(256) void k_agg64(const float* __restrict__ h,
                                               const int* __restrict__ rowptr,
                                               const int2* __restrict__ ep,
                                               const float* __restrict__ dinv,
                                               float* __restrict__ agg, int n) {
    const int node = (blockIdx.x * 256 + threadIdx.x) >> 6;
    const int lane = threadIdx.x & 63;
    if (node >= n) return;
    const float di = dinv[node];
    float acc = h[(size_t)node * 64 + lane] * di * di;  // self loop
    const int lo = rowptr[node], hi = rowptr[node + 1];
    int i = lo;
    for (; i + 3 < hi; i += 4) {
        int2 p0 = ep[i], p1 = ep[i + 1], p2 = ep[i + 2], p3 = ep[i + 3];
        float v0 = h[(size_t)p0.x * 64 + lane];
        float v1 = h[(size_t)p1.x * 64 + lane];
        float v2 = h[(size_t)p2.x * 64 + lane];
        float v3 = h[(size_t)p3.x * 64 + lane];
        acc = fmaf(v0, __int_as_float(p0.y), acc);
        acc = fmaf(v1, __int_as_float(p1.y), acc);
        acc = fmaf(v2, __int_as_float(p2.y), acc);
        acc = fmaf(v3, __int_as_float(p3.y), acc);
    }
    for (; i < hi; ++i) {
        int2 p = ep[i];
        acc = fmaf(h[(size_t)p.x * 64 + lane], __int_as_float(p.y), acc);
    }
    agg[(size_t)node * 64 + lane] = acc;
}

// Gather-aggregate, F=16: one 16-lane group per node. x4 unroll.
__global__ __launch_bounds__(256) void k_agg16(const float* __restrict__ h,
                                               const int* __restrict__ rowptr,
                                               const int2* __restrict__ ep,
                                               const float* __restrict__ dinv,
                                               float* __restrict__ agg, int n) {
    const int node = (blockIdx.x * 256 + threadIdx.x) >> 4;
    const int lane = threadIdx.x & 15;
    if (node >= n) return;
    const float di = dinv[node];
    float acc = h[(size_t)node * 16 + lane] * di * di;  // self loop
    const int lo = rowptr[node], hi = rowptr[node + 1];
    int i = lo;
    for (; i + 3 < hi; i += 4) {
        int2 p0 = ep[i], p1 = ep[i + 1], p2 = ep[i + 2], p3 = ep[i + 3];
        float v0 = h[(size_t)p0.x * 16 + lane];
        float v1 = h[(size_t)p1.x * 16 + lane];
        float v2 = h[(size_t)p2.x * 16 + lane];
        float v3 = h[(size_t)p3.x * 16 + lane];
        acc = fmaf(v0, __int_as_float(p0.y), acc);
        acc = fmaf(v1, __int_as_float(p1.y), acc);
        acc = fmaf(v2, __int_as_float(p2.y), acc);
        acc = fmaf(v3, __int_as_float(p3.y), acc);
    }
    for (; i < hi; ++i) {
        int2 p = ep[i];
        acc = fmaf(h[(size_t)p.x * 16 + lane], __int_as_float(p.y), acc);
    }
    agg[(size_t)node * 16 + lane] = acc;
}

// h2[n][16] = relu(a[n][64] + b1) @ W[64][16]; bias+relu fused into LDS load.
__global__ __launch_bounds__(256) void k_gemm2(const float* __restrict__ a,
                                               const float* __restrict__ W,
                                               const float* __restrict__ b1,
                                               float* __restrict__ h2, int n) {
    __shared__ float Ws[64 * 16];
    __shared__ float xs[32][68];
    const int t = threadIdx.x;
    for (int i = t; i < 64 * 16; i += 256) Ws[i] = W[i];
    const int node0 = blockIdx.x * 32;
    for (int i = t; i < 32 * 64; i += 256) {
        int nn = i >> 6, kk = i & 63;
        int node = node0 + nn;
        xs[nn][kk] = (node < n) ? fmaxf(a[(size_t)node * 64 + kk] + b1[kk], 0.0f) : 0.0f;
    }
    __syncthreads();
    const int f = t & 15;
    const int ng = t >> 4;  // 0..15
    float a0 = 0.f, a1 = 0.f;
#pragma unroll 4
    for (int k = 0; k < 64; ++k) {
        float wv = Ws[k * 16 + f];
        a0 = fmaf(xs[ng][k], wv, a0);
        a1 = fmaf(xs[ng + 16][k], wv, a1);
    }
    if (node0 + ng < n)      h2[(size_t)(node0 + ng) * 16 + f] = a0;
    if (node0 + ng + 16 < n) h2[(size_t)(node0 + ng + 16) * 16 + f] = a1;
}

// In-place: out[i][:] = log_softmax(out[i][:] + b2)
__global__ void k_logsoftmax(float* __restrict__ out, const float* __restrict__ b2, int n) {
    int i = blockIdx.x * blockDim.x + threadIdx.x;
    if (i >= n) return;
    const size_t base = (size_t)i * 16;
    float v[16];
#pragma unroll
    for (int f = 0; f < 16; ++f) v[f] = out[base + f] + b2[f];
    float m = v[0];
#pragma unroll
    for (int f = 1; f < 16; ++f) m = fmaxf(m, v[f]);
    float s = 0.f;
#pragma unroll
    for (int f = 0; f < 16; ++f) s += __expf(v[f] - m);
    float lse = __logf(s);
#pragma unroll
    for (int f = 0; f < 16; ++f) out[base + f] = v[f] - m - lse;
}

extern "C" void kernel_launch(void* const* d_in, const int* in_sizes, int n_in,
                              void* d_out, int out_size, void* d_ws, size_t ws_size,
                              hipStream_t stream) {
    const float* x  = (const float*)d_in[0];
    const int*   ei = (const int*)d_in[1];   // [2, E]
    const float* ew = (const float*)d_in[2];
    const float* W1 = (const float*)d_in[3];
    const float* b1 = (const float*)d_in[4];
    const float* W2 = (const float*)d_in[5];
    const float* b2 = (const float*)d_in[6];
    float* out = (float*)d_out;

    const int n = in_sizes[0] / 128;  // 100000
    const int E = in_sizes[2];        // 1600000
    const int* srcv = ei;
    const int* dstv = ei + E;

    // Workspace layout (4B units, epack kept 8B-aligned):
    float* wsf = (float*)d_ws;
    size_t off = 0;
    float* dinv = wsf + off; off += n;
    float* h1   = wsf + off; off += (size_t)n * 64;   // reused as h2[n*16]
    float* agg1 = wsf + off; off += (size_t)n * 64;
    off = (off + 1) & ~(size_t)1;                     // 8B align
    int2* epack = (int2*)(wsf + off); off += (size_t)E * 2;
    int* rowptr = (int*)(wsf + off); off += n + 1;
    int* cnt    = (int*)(wsf + off); off += n;
    int* cursor = (int*)(wsf + off); off += n;
    int* bsum   = (int*)(wsf + off); off += 256;
    int* boff   = (int*)(wsf + off); off += 256;

    const int TB = 256;
    const int NB = (n + SCAN_CHUNK - 1) / SCAN_CHUNK;

    // degree + histogram in one pass; then dinv
    k_init<<<(n + TB - 1) / TB, TB, 0, stream>>>(dinv, cnt, n);
    k_deg_hist<<<(E + TB - 1) / TB, TB, 0, stream>>>(dstv, ew, dinv, cnt, E);
    k_rsqrt_<<<(n + TB - 1) / TB, TB, 0, stream>>>(dinv, n);

    // CSR build
    k_scanA<<<NB, SCAN_BS, 0, stream>>>(cnt, bsum, n);
    k_scanB<<<1, 128, 0, stream>>>(bsum, boff, rowptr, NB, n);
    k_scanC<<<NB, SCAN_BS, 0, stream>>>(cnt, boff, rowptr, cursor, n);
    k_build<<<(E + TB - 1) / TB, TB, 0, stream>>>(srcv, dstv, ew, dinv, cursor, epack, E);

    // layer 1
    k_gemm1<<<(n + 15) / 16, TB, 0, stream>>>(x, W1, h1, n);
    k_agg64<<<(n * 64 + TB - 1) / TB, TB, 0, stream>>>(h1, rowptr, epack, dinv, agg1, n);

    // layer 2 (h2 reuses h1 buffer)
    k_gemm2<<<(n + 31) / 32, TB, 0, stream>>>(agg1, W2, b1, h1, n);
    k_agg16<<<(n * 16 + TB - 1) / TB, TB, 0, stream>>>(h1, rowptr, epack, dinv, out, n);

    // epilogue
    k_logsoftmax<<<(n + TB - 1) / TB, TB, 0, stream>>>(out, b2, n);
}

// Round 4
// 483.049 us; speedup vs baseline: 3.8879x; 1.0712x over previous
//
#include <hip/hip_runtime.h>

// ---------------------------------------------------------------------------
// GCN 2-layer, CSR-gather formulation. R4:
//  - histogram-only atomic pass (deg computed post-CSR by segmented sum)
//  - cnt/cursor padded to stride-4 ints (4x fewer atomics per 64B line)
//  - gemm1 fused into the hist dispatch (parity split: even=hist, odd=gemm)
//  - norm = dinv[src]*ew*dinv[dst] computed on the fly in agg kernels
// ---------------------------------------------------------------------------

#define SCAN_BS 256
#define SCAN_ITEMS 4
#define SCAN_CHUNK (SCAN_BS * SCAN_ITEMS)  // 1024

// Fused: role = blockIdx & 1. Even blocks: histogram (1 int atomic/edge).
// Odd blocks: h[n][64] = x[n][128] @ W[128][64], W LDS-resident, 16 nodes/blk.
__global__ __launch_bounds__(256) void k_histgemm1(
    const int* __restrict__ dst, int* __restrict__ cnt4, int E, int NBH,
    const float* __restrict__ x, const float* __restrict__ W,
    float* __restrict__ h, int n, int NBG) {
    __shared__ float Ws[128 * 64];
    __shared__ float xs[16][128];
    const int role = blockIdx.x & 1;
    const int idx = blockIdx.x >> 1;
    const int t = threadIdx.x;
    if (role == 0) {
        if (idx >= NBH) return;
        int e = idx * 256 + t;
        if (e < E) atomicAdd(&cnt4[dst[e] * 4], 1);
        return;
    }
    if (idx >= NBG) return;
    for (int i = t; i < 128 * 64; i += 256) Ws[i] = W[i];
    const int node0 = idx * 16;
    for (int i = t; i < 16 * 128; i += 256) {
        int nn = i >> 7, kk = i & 127;
        int node = node0 + nn;
        xs[nn][kk] = (node < n) ? x[(size_t)node * 128 + kk] : 0.0f;
    }
    __syncthreads();
    const int f = t & 63;
    const int ng = t >> 6;  // 0..3; whole wave shares ng -> xs reads broadcast
    float a0 = 0.f, a1 = 0.f, a2 = 0.f, a3 = 0.f;
#pragma unroll 4
    for (int k = 0; k < 128; ++k) {
        float wv = Ws[k * 64 + f];
        a0 = fmaf(xs[ng][k], wv, a0);
        a1 = fmaf(xs[ng + 4][k], wv, a1);
        a2 = fmaf(xs[ng + 8][k], wv, a2);
        a3 = fmaf(xs[ng + 12][k], wv, a3);
    }
    if (node0 + ng < n)      h[(size_t)(node0 + ng) * 64 + f] = a0;
    if (node0 + ng + 4 < n)  h[(size_t)(node0 + ng + 4) * 64 + f] = a1;
    if (node0 + ng + 8 < n)  h[(size_t)(node0 + ng + 8) * 64 + f] = a2;
    if (node0 + ng + 12 < n) h[(size_t)(node0 + ng + 12) * 64 + f] = a3;
}

// ---- 3-phase scan over strided cnt4[4*i] -> rowptr[n+1] + cursor4[4*i] ----
__global__ __launch_bounds__(SCAN_BS) void k_scanA(const int* __restrict__ cnt4,
                                                   int* __restrict__ bsum, int n) {
    __shared__ int red[SCAN_BS];
    const int b = blockIdx.x, t = threadIdx.x;
    const int base = b * SCAN_CHUNK + t * SCAN_ITEMS;
    int s = 0;
#pragma unroll
    for (int j = 0; j < SCAN_ITEMS; ++j) {
        int i = base + j;
        if (i < n) s += cnt4[i * 4];
    }
    red[t] = s;
    __syncthreads();
    for (int off = SCAN_BS / 2; off > 0; off >>= 1) {
        if (t < off) red[t] += red[t + off];
        __syncthreads();
    }
    if (t == 0) bsum[b] = red[0];
}

__global__ __launch_bounds__(128) void k_scanB(const int* __restrict__ bsum,
                                               int* __restrict__ boff,
                                               int* __restrict__ rowptr, int nb, int n) {
    __shared__ int lds[128];
    const int t = threadIdx.x;
    int carry = 0;
    for (int base = 0; base < nb; base += 128) {
        int idx = base + t;
        int v = (idx < nb) ? bsum[idx] : 0;
        lds[t] = v;
        __syncthreads();
        for (int off = 1; off < 128; off <<= 1) {
            int u = (t >= off) ? lds[t - off] : 0;
            __syncthreads();
            lds[t] += u;
            __syncthreads();
        }
        if (idx < nb) boff[idx] = lds[t] - v + carry;
        carry += lds[127];
        __syncthreads();
    }
    if (t == 0) rowptr[n] = carry;
}

__global__ __launch_bounds__(SCAN_BS) void k_scanC(const int* __restrict__ cnt4,
                                                   const int* __restrict__ boff,
                                                   int* __restrict__ rowptr,
                                                   int* __restrict__ cursor4, int n) {
    __shared__ int lds[SCAN_BS];
    const int b = blockIdx.x, t = threadIdx.x;
    const int base = b * SCAN_CHUNK + t * SCAN_ITEMS;
    int v[SCAN_ITEMS];
    int s = 0;
#pragma unroll
    for (int j = 0; j < SCAN_ITEMS; ++j) {
        int i = base + j;
        v[j] = (i < n) ? cnt4[i * 4] : 0;
        s += v[j];
    }
    lds[t] = s;
    __syncthreads();
    for (int off = 1; off < SCAN_BS; off <<= 1) {
        int u = (t >= off) ? lds[t - off] : 0;
        __syncthreads();
        lds[t] += u;
        __syncthreads();
    }
    int excl = lds[t] - s + boff[b];
#pragma unroll
    for (int j = 0; j < SCAN_ITEMS; ++j) {
        int i = base + j;
        if (i < n) {
            rowptr[i] = excl;
            cursor4[i * 4] = excl;
            excl += v[j];
        }
    }
}

// Bucket edges by dst: epack[p] = {src, bitcast(ew)} — single 8B store.
__global__ void k_build(const int* __restrict__ src, const int* __restrict__ dst,
                        const float* __restrict__ ew, int* __restrict__ cursor4,
                        int2* __restrict__ epack, int E) {
    int e = blockIdx.x * blockDim.x + threadIdx.x;
    if (e >= E) return;
    int d = dst[e];
    int p = atomicAdd(&cursor4[d * 4], 1);
    int2 pk;
    pk.x = src[e];
    pk.y = __float_as_int(ew[e]);
    epack[p] = pk;
}

// dinv[i] = rsqrt(1 + sum of ew over row i). One thread per node; rows are
// contiguous so neighboring threads touch neighboring lines.
__global__ void k_dinv(const int* __restrict__ rowptr, const int2* __restrict__ ep,
                       float* __restrict__ dinv, int n) {
    int i = blockIdx.x * blockDim.x + threadIdx.x;
    if (i >= n) return;
    int lo = rowptr[i], hi = rowptr[i + 1];
    float s = 1.0f;  // self loop
    for (int e = lo; e < hi; ++e) s += __int_as_float(ep[e].y);
    dinv[i] = rsqrtf(s);
}

// Gather-aggregate, F=64: one wave per node, lane = feature.
// acc_e accumulates h[src]*dinv[src]*ew; final = (h_self*di + acc_e)*di.
__global__ __launch_bounds__(256) void k_agg64(const float* __restrict__ h,
                                               const int* __restrict__ rowptr,
                                               const int2* __restrict__ ep,
                                               const float* __restrict__ dinv,
                                               float* __restrict__ agg, int n) {
    const int node = (blockIdx.x * 256 + threadIdx.x) >> 6;
    const int lane = threadIdx.x & 63;
    if (node >= n) return;
    const float di = dinv[node];
    float accE = 0.f;
    const int lo = rowptr[node], hi = rowptr[node + 1];
    int i = lo;
    for (; i + 3 < hi; i += 4) {
        int2 p0 = ep[i], p1 = ep[i + 1], p2 = ep[i + 2], p3 = ep[i + 3];
        float w0 = dinv[p0.x] * __int_as_float(p0.y);
        float w1 = dinv[p1.x] * __int_as_float(p1.y);
        float w2 = dinv[p2.x] * __int_as_float(p2.y);
        float w3 = dinv[p3.x] * __int_as_float(p3.y);
        float v0 = h[(size_t)p0.x * 64 + lane];
        float v1 = h[(size_t)p1.x * 64 + lane];
        float v2 = h[(size_t)p2.x * 64 + lane];
        float v3 = h[(size_t)p3.x * 64 + lane];
        accE = fmaf(v0, w0, accE);
        accE = fmaf(v1, w1, accE);
        accE = fmaf(v2, w2, accE);
        accE = fmaf(v3, w3, accE);
    }
    for (; i < hi; ++i) {
        int2 p = ep[i];
        accE = fmaf(h[(size_t)p.x * 64 + lane], dinv[p.x] * __int_as_float(p.y), accE);
    }
    float self = h[(size_t)node * 64 + lane];
    agg[(size_t)node * 64 + lane] = (fmaf(self, di, accE)) * di;
}

// Gather-aggregate, F=16: one 16-lane group per node.
__global__ __launch_bounds__(256) void k_agg16(const float* __restrict__ h,
                                               const int* __restrict__ rowptr,
                                               const int2* __restrict__ ep,
                                               const float* __restrict__ dinv,
                                               float* __restrict__ agg, int n) {
    const int node = (blockIdx.x * 256 + threadIdx.x) >> 4;
    const int lane = threadIdx.x & 15;
    if (node >= n) return;
    const float di = dinv[node];
    float accE = 0.f;
    const int lo = rowptr[node], hi = rowptr[node + 1];
    int i = lo;
    for (; i + 3 < hi; i += 4) {
        int2 p0 = ep[i], p1 = ep[i + 1], p2 = ep[i + 2], p3 = ep[i + 3];
        float w0 = dinv[p0.x] * __int_as_float(p0.y);
        float w1 = dinv[p1.x] * __int_as_float(p1.y);
        float w2 = dinv[p2.x] * __int_as_float(p2.y);
        float w3 = dinv[p3.x] * __int_as_float(p3.y);
        float v0 = h[(size_t)p0.x * 16 + lane];
        float v1 = h[(size_t)p1.x * 16 + lane];
        float v2 = h[(size_t)p2.x * 16 + lane];
        float v3 = h[(size_t)p3.x * 16 + lane];
        accE = fmaf(v0, w0, accE);
        accE = fmaf(v1, w1, accE);
        accE = fmaf(v2, w2, accE);
        accE = fmaf(v3, w3, accE);
    }
    for (; i < hi; ++i) {
        int2 p = ep[i];
        accE = fmaf(h[(size_t)p.x * 16 + lane], dinv[p.x] * __int_as_float(p.y), accE);
    }
    float self = h[(size_t)node * 16 + lane];
    agg[(size_t)node * 16 + lane] = (fmaf(self, di, accE)) * di;
}

// h2[n][16] = relu(a[n][64] + b1) @ W[64][16]; bias+relu fused into LDS load.
__global__ __launch_bounds__(256) void k_gemm2(const float* __restrict__ a,
                                               const float* __restrict__ W,
                                               const float* __restrict__ b1,
                                               float* __restrict__ h2, int n) {
    __shared__ float Ws[64 * 16];
    __shared__ float xs[32][68];
    const int t = threadIdx.x;
    for (int i = t; i < 64 * 16; i += 256) Ws[i] = W[i];
    const int node0 = blockIdx.x * 32;
    for (int i = t; i < 32 * 64; i += 256) {
        int nn = i >> 6, kk = i & 63;
        int node = node0 + nn;
        xs[nn][kk] = (node < n) ? fmaxf(a[(size_t)node * 64 + kk] + b1[kk], 0.0f) : 0.0f;
    }
    __syncthreads();
    const int f = t & 15;
    const int ng = t >> 4;  // 0..15
    float a0 = 0.f, a1 = 0.f;
#pragma unroll 4
    for (int k = 0; k < 64; ++k) {
        float wv = Ws[k * 16 + f];
        a0 = fmaf(xs[ng][k], wv, a0);
        a1 = fmaf(xs[ng + 16][k], wv, a1);
    }
    if (node0 + ng < n)      h2[(size_t)(node0 + ng) * 16 + f] = a0;
    if (node0 + ng + 16 < n) h2[(size_t)(node0 + ng + 16) * 16 + f] = a1;
}

// In-place: out[i][:] = log_softmax(out[i][:] + b2)
__global__ void k_logsoftmax(float* __restrict__ out, const float* __restrict__ b2, int n) {
    int i = blockIdx.x * blockDim.x + threadIdx.x;
    if (i >= n) return;
    const size_t base = (size_t)i * 16;
    float v[16];
#pragma unroll
    for (int f = 0; f < 16; ++f) v[f] = out[base + f] + b2[f];
    float m = v[0];
#pragma unroll
    for (int f = 1; f < 16; ++f) m = fmaxf(m, v[f]);
    float s = 0.f;
#pragma unroll
    for (int f = 0; f < 16; ++f) s += __expf(v[f] - m);
    float lse = __logf(s);
#pragma unroll
    for (int f = 0; f < 16; ++f) out[base + f] = v[f] - m - lse;
}

extern "C" void kernel_launch(void* const* d_in, const int* in_sizes, int n_in,
                              void* d_out, int out_size, void* d_ws, size_t ws_size,
                              hipStream_t stream) {
    const float* x  = (const float*)d_in[0];
    const int*   ei = (const int*)d_in[1];   // [2, E]
    const float* ew = (const float*)d_in[2];
    const float* W1 = (const float*)d_in[3];
    const float* b1 = (const float*)d_in[4];
    const float* W2 = (const float*)d_in[5];
    const float* b2 = (const float*)d_in[6];
    float* out = (float*)d_out;

    const int n = in_sizes[0] / 128;  // 100000
    const int E = in_sizes[2];        // 1600000
    const int* srcv = ei;
    const int* dstv = ei + E;

    // Workspace (4B units). cnt4/cursor4 alias agg1's region (dead by agg64).
    float* wsf = (float*)d_ws;
    size_t off = 0;
    float* dinv = wsf + off; off += n;
    float* h1   = wsf + off; off += (size_t)n * 64;   // reused as h2[n*16]
    float* agg1 = wsf + off; off += (size_t)n * 64;
    off = (off + 1) & ~(size_t)1;                     // 8B align
    int2* epack = (int2*)(wsf + off); off += (size_t)E * 2;
    int* rowptr = (int*)(wsf + off); off += n + 1;
    int* bsum   = (int*)(wsf + off); off += 1024;
    int* boff   = (int*)(wsf + off); off += 1024;
    int* cnt4    = (int*)agg1;        // [4n], stride-4
    int* cursor4 = (int*)agg1 + 4 * (size_t)n;  // [4n], stride-4

    const int TB = 256;
    const int NBH = (E + 255) / 256;      // hist blocks
    const int NBG = (n + 15) / 16;        // gemm1 blocks
    const int NBmax = NBH > NBG ? NBH : NBG;
    const int NBs = (n + SCAN_CHUNK - 1) / SCAN_CHUNK;

    // cnt4 = 0, then fused histogram + gemm1 (parity-interleaved roles)
    hipMemsetAsync(cnt4, 0, (size_t)4 * n * sizeof(int), stream);
    k_histgemm1<<<2 * NBmax, TB, 0, stream>>>(dstv, cnt4, E, NBH, x, W1, h1, n, NBG);

    // CSR build
    k_scanA<<<NBs, SCAN_BS, 0, stream>>>(cnt4, bsum, n);
    k_scanB<<<1, 128, 0, stream>>>(bsum, boff, rowptr, NBs, n);
    k_scanC<<<NBs, SCAN_BS, 0, stream>>>(cnt4, boff, rowptr, cursor4, n);
    k_build<<<(E + TB - 1) / TB, TB, 0, stream>>>(srcv, dstv, ew, cursor4, epack, E);

    // weighted degree -> dinv (coalesced segmented sum, no atomics)
    k_dinv<<<(n + TB - 1) / TB, TB, 0, stream>>>(rowptr, epack, dinv, n);

    // layer 1 aggregation
    k_agg64<<<(n * 64 + TB - 1) / TB, TB, 0, stream>>>(h1, rowptr, epack, dinv, agg1, n);

    // layer 2 (h2 reuses h1 buffer)
    k_gemm2<<<(n + 31) / 32, TB, 0, stream>>>(agg1, W2, b1, h1, n);
    k_agg16<<<(n * 16 + TB - 1) / TB, TB, 0, stream>>>(h1, rowptr, epack, dinv, out, n);

    // epilogue
    k_logsoftmax<<<(n + TB - 1) / TB, TB, 0, stream>>>(out, b2, n);
}